// Round 13
// baseline (79.176 us; speedup 1.0000x reference)
//
#include <hip/hip_runtime.h>

// CRF-RNN (C=2) on 56x56, 10 iterations in ONE kernel, plain launch.
// 196 blocks x 512 thr (8 waves) -> EXACTLY 1 block/CU (uniform: no
// CU-sharing skew at the zero-sentinel syncs; r12 had 136 CUs carrying 2
// blocks, making every sync wait ~2x compute), 2 waves/SIMD latency hiding.
// Per-thread work identical to r12 (which r10's 256-thr version doubled).
//
// Math: s = sigmoid(q1-q0); d = (2u-1) - alpha - beta*t_sp/n_sp - gamma*t_bl/n_bl.
//  * spatial separable: 56-tap row conv (aligned per-j weight rows) +
//    column fold; n_sp = Sx*Sy exactly.
//  * bilateral: theta_beta=3 -> weight < 5e-17 outside +-16 intensity
//    buckets. Counting sort by intensity ONCE; band loop walks m_srt[p]
//    (u16) and reads s_sh[m] directly (magic-mul recovers x,y).
//  * norms s-independent: iter-0 computes them, reciprocals in registers.
//
// Sync: zero-sentinel flow control (r8/r12): sigmoid outputs are never 0.0f;
// 9 distinct pre-zeroed publish buffers; publish = 16 relaxed agent stores
// issued by the j-leader lanes BEFORE the block barrier (latency hidden);
// consume = 512 threads poll 1-2 quads each w/ global_load_dwordx4 sc0 sc1,
// per-thread done flags, 8-wave vote via LDS flags; restage contiguous.

namespace {

constexpr int NPIX = 3136;
constexpr int WIMG = 56;
constexpr int JPB  = 16;              // j-pixels per block
constexpr int NBLK = NPIX / JPB;      // 196 blocks = 1 per CU
constexpr int NTHR = 512;             // 8 waves
constexpr int NQ   = NPIX / 4;        // 784 quads
constexpr int NBUF = 9;               // publish buffers (syncs after iters 0..8)
constexpr int BAND = 16;              // intensity band (buckets)
constexpr int Q2   = NQ - NTHR;       // 272 threads own a second quad

constexpr float LOG2E = 1.4426950408889634f;
constexpr float C1 = -LOG2E / 18.0f;      // spatial exponent coeff
constexpr float C2 = -LOG2E / 51200.0f;   // bilateral spatial coeff
constexpr float C3 = -LOG2E / 6.0f;       // bilateral intensity coeff

// LDS pool layout (bytes, 16-aligned)
constexpr int O_SSH  = 0;         // float[3136] s, linear image order
constexpr int O_GSRT = 12544;     // float[3136] g, sorted order
                                  // (init: H u16[49][256]=25088B overlays SSH+GSRT)
constexpr int O_MSRT = 25088;     // u16[3136]  sorted pos -> linear pixel idx
constexpr int O_OFF  = 31360;     // u32[257]   bucket offsets (pad 1040)
constexpr int O_WSX  = 32400;     // float[16][56] per-j row weights (aligned)
constexpr int O_WSY  = 35984;     // float[16][56] per-j column weights
constexpr int O_ROWC = 39568;     // float[56][17] row-conv out (pad stride 17)
constexpr int O_WFLG = 43376;     // int[8]
constexpr int POOLSZ = 43408;

#define REDUCE32(v) \
    { v += __shfl_xor(v, 1); v += __shfl_xor(v, 2); v += __shfl_xor(v, 4); \
      v += __shfl_xor(v, 8); v += __shfl_xor(v, 16); }

__global__ __launch_bounds__(NTHR) void crf_all(
    const float* __restrict__ inp,
    const float* __restrict__ spw, const float* __restrict__ blw,
    const float* __restrict__ cmw,
    float* sbufs, float* __restrict__ out)
{
    __shared__ __align__(16) unsigned char pool[POOLSZ];
    float*  s_sh  = (float*)(pool + O_SSH);
    float4* s_sh4 = (float4*)(pool + O_SSH);
    float*  g_srt = (float*)(pool + O_GSRT);
    unsigned short* m_srt = (unsigned short*)(pool + O_MSRT);
    unsigned*       offs  = (unsigned*)(pool + O_OFF);
    float*  wsx   = (float*)(pool + O_WSX);
    float*  wsy   = (float*)(pool + O_WSY);
    float*  rowc  = (float*)(pool + O_ROWC);
    int*    wflag = (int*)(pool + O_WFLG);
    unsigned short* H  = (unsigned short*)(pool + O_SSH);   // init union (25088B)
    unsigned*       Hz = (unsigned*)(pool + O_SSH);

    const int t   = threadIdx.x;
    const int bid = blockIdx.x;
    const int sub = t & 31;
    const int jl  = t >> 5;               // 0..15
    const int j   = bid * JPB + jl;
    const int xj  = j % WIMG;             // blocks may straddle rows (16 ∤ 56)
    const int yj  = j / WIMG;
    const float xjf = (float)xj, yjf = (float)yj;

    const float uj = inp[j];
    const float gj = inp[NPIX + j] * 255.0f;

    // collapse the 2x2 weight matrices to 3 scalars
    const float e0 = cmw[2] - cmw[0];
    const float e1 = cmw[3] - cmw[1];
    const float alpha = e0 * (spw[0] + blw[0]) + e1 * (spw[2] + blw[2]);
    const float beta  = e0 * (spw[1] - spw[0]) + e1 * (spw[3] - spw[2]);
    const float gamma = e0 * (blw[1] - blw[0]) + e1 * (blw[3] - blw[2]);

    // ---- I0: zero H; build aligned per-j weight tables (outside H region)
    for (int i = t; i < 6272; i += NTHR) Hz[i] = 0u;
    for (int idx = t; idx < JPB * 56; idx += NTHR) {
        const int jlw = idx / 56, p = idx - jlw * 56;
        const int jj = bid * JPB + jlw;
        const float ddx = (float)(jj % WIMG - p);
        const float ddy = (float)(jj / WIMG - p);
        wsx[idx] = __builtin_amdgcn_exp2f(C1 * ddx * ddx);
        wsy[idx] = __builtin_amdgcn_exp2f(C1 * ddy * ddy);
    }
    __syncthreads();
    // ---- I1: per-chunk histogram (49 chunks x 64 px, single-owner rows)
    if (t < 49) {
        unsigned short* Hr = H + t * 256;
        const int mb = t * 64;
        for (int i = 0; i < 64; ++i) {
            int b = (int)(inp[NPIX + mb + i] * 255.0f);
            b = b > 255 ? 255 : b;
            Hr[b] = (unsigned short)(Hr[b] + 1);
        }
    }
    __syncthreads();
    // ---- I2: column prefix per bucket; totals -> offs[b]
    if (t < 256) {
        unsigned run = 0;
        for (int c = 0; c < 49; ++c) {
            unsigned short v = H[c * 256 + t];
            H[c * 256 + t] = (unsigned short)run;
            run += v;
        }
        offs[t] = run;
    }
    __syncthreads();
    // ---- I3: exclusive scan offs[0..255] (one wave, 4 buckets/lane)
    if (t < 64) {
        unsigned v0 = offs[4 * t], v1 = offs[4 * t + 1];
        unsigned v2 = offs[4 * t + 2], v3 = offs[4 * t + 3];
        unsigned sum = v0 + v1 + v2 + v3;
        unsigned sc = sum;
        for (int d = 1; d < 64; d <<= 1) {
            unsigned n = __shfl_up(sc, d);
            if (t >= d) sc += n;
        }
        unsigned base = sc - sum;
        offs[4 * t] = base;
        offs[4 * t + 1] = base + v0;
        offs[4 * t + 2] = base + v0 + v1;
        offs[4 * t + 3] = base + v0 + v1 + v2;
        if (t == 63) offs[256] = sc;               // = 3136
    }
    __syncthreads();
    // ---- I4: stable deterministic ranks -> m_srt
    if (t < 49) {
        unsigned short* Hr = H + t * 256;
        const int mb = t * 64;
        for (int i = 0; i < 64; ++i) {
            int b = (int)(inp[NPIX + mb + i] * 255.0f);
            b = b > 255 ? 255 : b;
            int r = (int)offs[b] + (int)Hr[b];
            Hr[b] = (unsigned short)(Hr[b] + 1);
            m_srt[r] = (unsigned short)(mb + i);
        }
    }
    __syncthreads();
    // ---- I5: H dead. Fill g_srt (sorted) and s_sh = u (linear).
    for (int p = t; p < NPIX; p += NTHR)
        g_srt[p] = inp[NPIX + (int)m_srt[p]] * 255.0f;
    {
        const float4* u4 = (const float4*)inp;
        for (int q = t; q < NQ; q += NTHR) s_sh4[q] = u4[q];
    }
    __syncthreads();

    // n_sp = Sx*Sy (exact separable)
    float sx, sy;
    {
        float dd = xjf - (float)sub;
        sx = __builtin_amdgcn_exp2f(C1 * dd * dd);
        if (sub + 32 < 56) {
            float d2 = xjf - (float)(sub + 32);
            sx += __builtin_amdgcn_exp2f(C1 * d2 * d2);
        }
        REDUCE32(sx);
        dd = yjf - (float)sub;
        sy = __builtin_amdgcn_exp2f(C1 * dd * dd);
        if (sub + 32 < 56) {
            float d2 = yjf - (float)(sub + 32);
            sy += __builtin_amdgcn_exp2f(C1 * d2 * d2);
        }
        REDUCE32(sy);
    }
    const float rnsp = 1.0f / (sx * sy);

    int bj = (int)gj; bj = bj > 255 ? 255 : bj;
    const int blo = (int)offs[bj < BAND ? 0 : bj - BAND];
    const int bhi = (int)offs[(bj + BAND > 255 ? 255 : bj + BAND) + 1];

    // separable spatial: row conv (56x16 = 896 outputs over 512 thr) + fold
    auto spatial = [&]() -> float {
        {
            const int y = t >> 4, c = t & 15;
            const float4* R = (const float4*)(wsx + c * 56);
            const float4* S = s_sh4 + y * 14;
            float acc = 0.f;
#pragma unroll
            for (int q = 0; q < 14; ++q) {
                float4 w = R[q], sv = S[q];
                acc = fmaf(w.x, sv.x, acc); acc = fmaf(w.y, sv.y, acc);
                acc = fmaf(w.z, sv.z, acc); acc = fmaf(w.w, sv.w, acc);
            }
            rowc[y * 17 + c] = acc;
        }
        {
            const int idx = t + NTHR;           // 512..895
            if (idx < 56 * 16) {
                const int y = idx >> 4, c = idx & 15;
                const float4* R = (const float4*)(wsx + c * 56);
                const float4* S = s_sh4 + y * 14;
                float acc = 0.f;
#pragma unroll
                for (int q = 0; q < 14; ++q) {
                    float4 w = R[q], sv = S[q];
                    acc = fmaf(w.x, sv.x, acc); acc = fmaf(w.y, sv.y, acc);
                    acc = fmaf(w.z, sv.z, acc); acc = fmaf(w.w, sv.w, acc);
                }
                rowc[y * 17 + c] = acc;
            }
        }
        __syncthreads();
        const float* wy = wsy + jl * 56;
        float part = wy[sub] * rowc[sub * 17 + jl];
        if (sub + 32 < 56)
            part = fmaf(wy[sub + 32], rowc[(sub + 32) * 17 + jl], part);
        REDUCE32(part);
        return part;
    };

    // bilateral band pass over sorted positions [blo,bhi), stride 32
    auto bilateral = [&](float* nacc_out) -> float {
        float acc = 0.f, nacc = 0.f;
        for (int p = blo + sub; p < bhi; p += 32) {
            const int m = (int)m_srt[p];
            const float gv = g_srt[p];
            const float sv = s_sh[m];
            const int yi = (m * 9363) >> 19;       // m/56 (exact for m<3136)
            const int xi = m - yi * 56;
            const float ux = (float)xi - xjf, vy = (float)yi - yjf;
            const float r2 = fmaf(ux, ux, vy * vy);
            const float dg = gv - gj;
            const float w = __builtin_amdgcn_exp2f(fmaf(dg * C3, dg, r2 * C2));
            acc = fmaf(w, sv, acc);
            if (nacc_out) nacc += w;
        }
        REDUCE32(acc);
        if (nacc_out) { REDUCE32(nacc); *nacc_out = nacc; }
        return acc;
    };

    // publish (leader lanes, pre-barrier) + zero-sentinel poll + restage
    auto publish_sync = [&](float s, float* buf) {
        if (sub == 0)                               // 16 stores, issued early
            __hip_atomic_store(&buf[j], s, __ATOMIC_RELAXED,
                               __HIP_MEMORY_SCOPE_AGENT);
        __syncthreads();                            // all compute done
        const float4* src = (const float4*)buf;
        float4 a, b;
        bool done = false;
        const bool two = (t < Q2);
        for (;;) {
            if (!done) {
                asm volatile("global_load_dwordx4 %0, %1, off sc0 sc1"
                             : "=&v"(a) : "v"(src + t));
                if (two)
                    asm volatile("global_load_dwordx4 %0, %1, off sc0 sc1"
                                 : "=&v"(b) : "v"(src + NTHR + t));
                asm volatile("s_waitcnt vmcnt(0)" ::: "memory");
                float mn = fminf(fminf(a.x, a.y), fminf(a.z, a.w));
                if (two)
                    mn = fminf(mn, fminf(fminf(b.x, b.y), fminf(b.z, b.w)));
                done = (mn != 0.0f);                // s values are > 0
            }
            const bool wall = (__all(done) != 0);
            if ((t & 63) == 0) wflag[t >> 6] = wall ? 1 : 0;
            __syncthreads();
            bool allw = true;
#pragma unroll
            for (int wv = 0; wv < 8; ++wv) allw = allw && (wflag[wv] != 0);
            if (allw) break;
            __syncthreads();
            __builtin_amdgcn_s_sleep(1);
        }
        s_sh4[t] = a;
        if (two) s_sh4[NTHR + t] = b;
        __syncthreads();
    };

    const float base = 2.0f * uj - 1.0f - alpha;
    float rnbl, s;

    // ---- iteration 0 (s = u), also accumulates n_bl over the band
    {
        float tsp = spatial();
        float nacc;
        float acc = bilateral(&nacc);
        rnbl = 1.0f / nacc;
        float d = base - beta * (tsp * rnsp) - gamma * (acc * rnbl);
        s = 1.0f / (1.0f + __builtin_amdgcn_exp2f(-d * LOG2E));
    }
    publish_sync(s, sbufs);

    // ---- iterations 1..9
    for (int k = 1; k < 10; ++k) {
        float tsp = spatial();
        float acc = bilateral(nullptr);
        float d = base - beta * (tsp * rnsp) - gamma * (acc * rnbl);
        s = 1.0f / (1.0f + __builtin_amdgcn_exp2f(-d * LOG2E));
        if (k < 9) publish_sync(s, sbufs + k * NPIX);
        else if (sub == 0) out[j] = s;   // softmax(q)[1] = sigmoid(d)
    }
}

}  // namespace

extern "C" void kernel_launch(void* const* d_in, const int* in_sizes, int n_in,
                              void* d_out, int out_size, void* d_ws, size_t ws_size,
                              hipStream_t stream) {
    const float* inp = (const float*)d_in[0];
    const float* spw = (const float*)d_in[1];
    const float* blw = (const float*)d_in[2];
    const float* cmw = (const float*)d_in[3];
    float* sbufs = (float*)d_ws;          // 9 x 3136 floats, zero = "not yet"
    float* out = (float*)d_out;

    hipMemsetAsync(sbufs, 0, NBUF * NPIX * sizeof(float), stream);
    crf_all<<<dim3(NBLK), dim3(NTHR), 0, stream>>>(inp, spw, blw, cmw,
                                                   sbufs, out);
}

// Round 14
// 65.600 us; speedup vs baseline: 1.2070x; 1.2070x over previous
//
#include <hip/hip_runtime.h>

// CRF-RNN (C=2) on 56x56, 10 iterations in ONE kernel, plain launch.
// 196 blocks x 512 thr (8 waves) -> exactly 1 block/CU, 2 waves/SIMD.
//
// Math: s = sigmoid(q1-q0); d = (2u-1) - alpha - beta*t_sp/n_sp - gamma*t_bl/n_bl.
//  * spatial separable: 56-tap row conv (aligned per-j weight rows) +
//    column fold; n_sp = Sx*Sy exactly.
//  * bilateral: theta_beta=3 -> weight < 5e-17 outside +-16 intensity
//    buckets. Counting sort by intensity ONCE; band loop walks m_srt[p]
//    (u16) and reads s_sh[m] directly (magic-mul recovers x,y).
//  * norms s-independent: iter-0 computes them, reciprocals in registers.
//
// Sync v6 -- zero-sentinel with PER-THREAD INDEPENDENT SPIN (r13 post-mortem:
// the block-wide vote cost 2x 8-wave __syncthreads + LDS flags PER POLL ROUND
// = ~4-6us/sync of overhead). Now: each thread owns 1-2 quads of the field,
// spins only on those (exec mask narrows the wave as lanes finish), writes
// them to LDS, then ONE final barrier. Publish = 16 relaxed agent stores by
// j-leader lanes issued as soon as s is known (global-only; distinct
// per-iteration buffers -> no WAR). Backoff s_sleep(4).

namespace {

constexpr int NPIX = 3136;
constexpr int WIMG = 56;
constexpr int JPB  = 16;              // j-pixels per block
constexpr int NBLK = NPIX / JPB;      // 196 blocks = 1 per CU
constexpr int NTHR = 512;             // 8 waves
constexpr int NQ   = NPIX / 4;        // 784 quads
constexpr int NBUF = 9;               // publish buffers (syncs after iters 0..8)
constexpr int BAND = 16;              // intensity band (buckets)
constexpr int Q2   = NQ - NTHR;       // 272 threads own a second quad

constexpr float LOG2E = 1.4426950408889634f;
constexpr float C1 = -LOG2E / 18.0f;      // spatial exponent coeff
constexpr float C2 = -LOG2E / 51200.0f;   // bilateral spatial coeff
constexpr float C3 = -LOG2E / 6.0f;       // bilateral intensity coeff

// LDS pool layout (bytes, 16-aligned)
constexpr int O_SSH  = 0;         // float[3136] s, linear image order
constexpr int O_GSRT = 12544;     // float[3136] g, sorted order
                                  // (init: H u16[49][256]=25088B overlays SSH+GSRT)
constexpr int O_MSRT = 25088;     // u16[3136]  sorted pos -> linear pixel idx
constexpr int O_OFF  = 31360;     // u32[257]   bucket offsets (pad 1040)
constexpr int O_WSX  = 32400;     // float[16][56] per-j row weights (aligned)
constexpr int O_WSY  = 35984;     // float[16][56] per-j column weights
constexpr int O_ROWC = 39568;     // float[56][17] row-conv out (pad stride 17)
constexpr int POOLSZ = 43376;

#define REDUCE32(v) \
    { v += __shfl_xor(v, 1); v += __shfl_xor(v, 2); v += __shfl_xor(v, 4); \
      v += __shfl_xor(v, 8); v += __shfl_xor(v, 16); }

__global__ __launch_bounds__(NTHR) void crf_all(
    const float* __restrict__ inp,
    const float* __restrict__ spw, const float* __restrict__ blw,
    const float* __restrict__ cmw,
    float* sbufs, float* __restrict__ out)
{
    __shared__ __align__(16) unsigned char pool[POOLSZ];
    float*  s_sh  = (float*)(pool + O_SSH);
    float4* s_sh4 = (float4*)(pool + O_SSH);
    float*  g_srt = (float*)(pool + O_GSRT);
    unsigned short* m_srt = (unsigned short*)(pool + O_MSRT);
    unsigned*       offs  = (unsigned*)(pool + O_OFF);
    float*  wsx   = (float*)(pool + O_WSX);
    float*  wsy   = (float*)(pool + O_WSY);
    float*  rowc  = (float*)(pool + O_ROWC);
    unsigned short* H  = (unsigned short*)(pool + O_SSH);   // init union (25088B)
    unsigned*       Hz = (unsigned*)(pool + O_SSH);

    const int t   = threadIdx.x;
    const int bid = blockIdx.x;
    const int sub = t & 31;
    const int jl  = t >> 5;               // 0..15
    const int j   = bid * JPB + jl;
    const int xj  = j % WIMG;             // blocks may straddle rows (16 ∤ 56)
    const int yj  = j / WIMG;
    const float xjf = (float)xj, yjf = (float)yj;

    const float uj = inp[j];
    const float gj = inp[NPIX + j] * 255.0f;

    // collapse the 2x2 weight matrices to 3 scalars
    const float e0 = cmw[2] - cmw[0];
    const float e1 = cmw[3] - cmw[1];
    const float alpha = e0 * (spw[0] + blw[0]) + e1 * (spw[2] + blw[2]);
    const float beta  = e0 * (spw[1] - spw[0]) + e1 * (spw[3] - spw[2]);
    const float gamma = e0 * (blw[1] - blw[0]) + e1 * (blw[3] - blw[2]);

    // ---- I0: zero H; build aligned per-j weight tables (outside H region)
    for (int i = t; i < 6272; i += NTHR) Hz[i] = 0u;
    for (int idx = t; idx < JPB * 56; idx += NTHR) {
        const int jlw = idx / 56, p = idx - jlw * 56;
        const int jj = bid * JPB + jlw;
        const float ddx = (float)(jj % WIMG - p);
        const float ddy = (float)(jj / WIMG - p);
        wsx[idx] = __builtin_amdgcn_exp2f(C1 * ddx * ddx);
        wsy[idx] = __builtin_amdgcn_exp2f(C1 * ddy * ddy);
    }
    __syncthreads();
    // ---- I1: per-chunk histogram (49 chunks x 64 px, single-owner rows)
    if (t < 49) {
        unsigned short* Hr = H + t * 256;
        const int mb = t * 64;
        for (int i = 0; i < 64; ++i) {
            int b = (int)(inp[NPIX + mb + i] * 255.0f);
            b = b > 255 ? 255 : b;
            Hr[b] = (unsigned short)(Hr[b] + 1);
        }
    }
    __syncthreads();
    // ---- I2: column prefix per bucket; totals -> offs[b]
    if (t < 256) {
        unsigned run = 0;
        for (int c = 0; c < 49; ++c) {
            unsigned short v = H[c * 256 + t];
            H[c * 256 + t] = (unsigned short)run;
            run += v;
        }
        offs[t] = run;
    }
    __syncthreads();
    // ---- I3: exclusive scan offs[0..255] (one wave, 4 buckets/lane)
    if (t < 64) {
        unsigned v0 = offs[4 * t], v1 = offs[4 * t + 1];
        unsigned v2 = offs[4 * t + 2], v3 = offs[4 * t + 3];
        unsigned sum = v0 + v1 + v2 + v3;
        unsigned sc = sum;
        for (int d = 1; d < 64; d <<= 1) {
            unsigned n = __shfl_up(sc, d);
            if (t >= d) sc += n;
        }
        unsigned base = sc - sum;
        offs[4 * t] = base;
        offs[4 * t + 1] = base + v0;
        offs[4 * t + 2] = base + v0 + v1;
        offs[4 * t + 3] = base + v0 + v1 + v2;
        if (t == 63) offs[256] = sc;               // = 3136
    }
    __syncthreads();
    // ---- I4: stable deterministic ranks -> m_srt
    if (t < 49) {
        unsigned short* Hr = H + t * 256;
        const int mb = t * 64;
        for (int i = 0; i < 64; ++i) {
            int b = (int)(inp[NPIX + mb + i] * 255.0f);
            b = b > 255 ? 255 : b;
            int r = (int)offs[b] + (int)Hr[b];
            Hr[b] = (unsigned short)(Hr[b] + 1);
            m_srt[r] = (unsigned short)(mb + i);
        }
    }
    __syncthreads();
    // ---- I5: H dead. Fill g_srt (sorted) and s_sh = u (linear).
    for (int p = t; p < NPIX; p += NTHR)
        g_srt[p] = inp[NPIX + (int)m_srt[p]] * 255.0f;
    {
        const float4* u4 = (const float4*)inp;
        for (int q = t; q < NQ; q += NTHR) s_sh4[q] = u4[q];
    }
    __syncthreads();

    // n_sp = Sx*Sy (exact separable)
    float sx, sy;
    {
        float dd = xjf - (float)sub;
        sx = __builtin_amdgcn_exp2f(C1 * dd * dd);
        if (sub + 32 < 56) {
            float d2 = xjf - (float)(sub + 32);
            sx += __builtin_amdgcn_exp2f(C1 * d2 * d2);
        }
        REDUCE32(sx);
        dd = yjf - (float)sub;
        sy = __builtin_amdgcn_exp2f(C1 * dd * dd);
        if (sub + 32 < 56) {
            float d2 = yjf - (float)(sub + 32);
            sy += __builtin_amdgcn_exp2f(C1 * d2 * d2);
        }
        REDUCE32(sy);
    }
    const float rnsp = 1.0f / (sx * sy);

    int bj = (int)gj; bj = bj > 255 ? 255 : bj;
    const int blo = (int)offs[bj < BAND ? 0 : bj - BAND];
    const int bhi = (int)offs[(bj + BAND > 255 ? 255 : bj + BAND) + 1];

    // separable spatial: row conv (56x16 = 896 outputs over 512 thr) + fold
    auto spatial = [&]() -> float {
        {
            const int y = t >> 4, c = t & 15;
            const float4* R = (const float4*)(wsx + c * 56);
            const float4* S = s_sh4 + y * 14;
            float acc = 0.f;
#pragma unroll
            for (int q = 0; q < 14; ++q) {
                float4 w = R[q], sv = S[q];
                acc = fmaf(w.x, sv.x, acc); acc = fmaf(w.y, sv.y, acc);
                acc = fmaf(w.z, sv.z, acc); acc = fmaf(w.w, sv.w, acc);
            }
            rowc[y * 17 + c] = acc;
        }
        {
            const int idx = t + NTHR;           // 512..895
            if (idx < 56 * 16) {
                const int y = idx >> 4, c = idx & 15;
                const float4* R = (const float4*)(wsx + c * 56);
                const float4* S = s_sh4 + y * 14;
                float acc = 0.f;
#pragma unroll
                for (int q = 0; q < 14; ++q) {
                    float4 w = R[q], sv = S[q];
                    acc = fmaf(w.x, sv.x, acc); acc = fmaf(w.y, sv.y, acc);
                    acc = fmaf(w.z, sv.z, acc); acc = fmaf(w.w, sv.w, acc);
                }
                rowc[y * 17 + c] = acc;
            }
        }
        __syncthreads();
        const float* wy = wsy + jl * 56;
        float part = wy[sub] * rowc[sub * 17 + jl];
        if (sub + 32 < 56)
            part = fmaf(wy[sub + 32], rowc[(sub + 32) * 17 + jl], part);
        REDUCE32(part);
        return part;
    };

    // bilateral band pass over sorted positions [blo,bhi), stride 32
    auto bilateral = [&](float* nacc_out) -> float {
        float acc = 0.f, nacc = 0.f;
        for (int p = blo + sub; p < bhi; p += 32) {
            const int m = (int)m_srt[p];
            const float gv = g_srt[p];
            const float sv = s_sh[m];
            const int yi = (m * 9363) >> 19;       // m/56 (exact for m<3136)
            const int xi = m - yi * 56;
            const float ux = (float)xi - xjf, vy = (float)yi - yjf;
            const float r2 = fmaf(ux, ux, vy * vy);
            const float dg = gv - gj;
            const float w = __builtin_amdgcn_exp2f(fmaf(dg * C3, dg, r2 * C2));
            acc = fmaf(w, sv, acc);
            if (nacc_out) nacc += w;
        }
        REDUCE32(acc);
        if (nacc_out) { REDUCE32(nacc); *nacc_out = nacc; }
        return acc;
    };

    // publish (leader lanes, immediate) + per-thread zero-sentinel spin
    auto publish_sync = [&](float s, float* buf) {
        if (sub == 0)                               // global-only; no barrier req
            __hip_atomic_store(&buf[j], s, __ATOMIC_RELAXED,
                               __HIP_MEMORY_SCOPE_AGENT);
        __syncthreads();                            // all done READING old s_sh
        const float4* src = (const float4*)buf;
        float4 a, b;
        const bool two = (t < Q2);
        bool da = false, db = !two;
        for (;;) {
            if (!da)
                asm volatile("global_load_dwordx4 %0, %1, off sc0 sc1"
                             : "=&v"(a) : "v"(src + t));
            if (!db)
                asm volatile("global_load_dwordx4 %0, %1, off sc0 sc1"
                             : "=&v"(b) : "v"(src + NTHR + t));
            asm volatile("s_waitcnt vmcnt(0)" ::: "memory");
            if (!da) da = (fminf(fminf(a.x, a.y), fminf(a.z, a.w)) != 0.0f);
            if (!db) db = (fminf(fminf(b.x, b.y), fminf(b.z, b.w)) != 0.0f);
            if (da && db) break;                    // exec mask narrows wave
            __builtin_amdgcn_s_sleep(4);
        }
        s_sh4[t] = a;
        if (two) s_sh4[NTHR + t] = b;
        __syncthreads();                            // s_sh fully fresh
    };

    const float base = 2.0f * uj - 1.0f - alpha;
    float rnbl, s;

    // ---- iteration 0 (s = u), also accumulates n_bl over the band
    {
        float tsp = spatial();
        float nacc;
        float acc = bilateral(&nacc);
        rnbl = 1.0f / nacc;
        float d = base - beta * (tsp * rnsp) - gamma * (acc * rnbl);
        s = 1.0f / (1.0f + __builtin_amdgcn_exp2f(-d * LOG2E));
    }
    publish_sync(s, sbufs);

    // ---- iterations 1..9
    for (int k = 1; k < 10; ++k) {
        float tsp = spatial();
        float acc = bilateral(nullptr);
        float d = base - beta * (tsp * rnsp) - gamma * (acc * rnbl);
        s = 1.0f / (1.0f + __builtin_amdgcn_exp2f(-d * LOG2E));
        if (k < 9) publish_sync(s, sbufs + k * NPIX);
        else if (sub == 0) out[j] = s;   // softmax(q)[1] = sigmoid(d)
    }
}

}  // namespace

extern "C" void kernel_launch(void* const* d_in, const int* in_sizes, int n_in,
                              void* d_out, int out_size, void* d_ws, size_t ws_size,
                              hipStream_t stream) {
    const float* inp = (const float*)d_in[0];
    const float* spw = (const float*)d_in[1];
    const float* blw = (const float*)d_in[2];
    const float* cmw = (const float*)d_in[3];
    float* sbufs = (float*)d_ws;          // 9 x 3136 floats, zero = "not yet"
    float* out = (float*)d_out;

    hipMemsetAsync(sbufs, 0, NBUF * NPIX * sizeof(float), stream);
    crf_all<<<dim3(NBLK), dim3(NTHR), 0, stream>>>(inp, spw, blw, cmw,
                                                   sbufs, out);
}

// Round 15
// 65.017 us; speedup vs baseline: 1.2178x; 1.0090x over previous
//
#include <hip/hip_runtime.h>

// CRF-RNN (C=2) on 56x56, 10 iterations in ONE kernel, plain launch.
// 196 blocks x 512 thr (8 waves) -> exactly 1 block/CU, 2 waves/SIMD.
//
// Math: s = sigmoid(q1-q0); d = (2u-1) - alpha - beta*t_sp/n_sp - gamma*t_bl/n_bl.
//  * spatial separable: 56-tap row conv (aligned per-j weight rows) +
//    column fold; n_sp = Sx*Sy exactly.
//  * bilateral: theta_beta=3 -> weight < 5e-17 outside +-16 intensity
//    buckets. Counting sort by intensity ONCE; band loop walks m_srt[p]
//    (u16) and reads s_sh[m] directly (magic-mul recovers x,y).
//  * norms s-independent: iter-0 computes them, reciprocals in registers.
//
// Sync v7 -- zero-sentinel, per-thread spin, TIGHT (r14 post-mortem: the
// s_sleep(4) quantization + pre-poll barrier were ~2.5us of each sync):
//  * publish: j-leader lanes store s right out of the reduce (relaxed agent
//    scope -> LLC, no cache maintenance), NO block barrier first. Safe:
//    detection of "all 3136 published" transitively implies every lane
//    everywhere finished reading old s_sh (shfl-reduce completes for the
//    leader only after all 32 group lanes executed their reads).
//  * poll: each thread re-issues its 1-2 quad loads (sc0 sc1) immediately,
//    no sleep -> detection ~= one load RT after the last store lands.
//  * restage + ONE barrier.

namespace {

constexpr int NPIX = 3136;
constexpr int WIMG = 56;
constexpr int JPB  = 16;              // j-pixels per block
constexpr int NBLK = NPIX / JPB;      // 196 blocks = 1 per CU
constexpr int NTHR = 512;             // 8 waves
constexpr int NQ   = NPIX / 4;        // 784 quads
constexpr int NBUF = 9;               // publish buffers (syncs after iters 0..8)
constexpr int BAND = 16;              // intensity band (buckets)
constexpr int Q2   = NQ - NTHR;       // 272 threads own a second quad

constexpr float LOG2E = 1.4426950408889634f;
constexpr float C1 = -LOG2E / 18.0f;      // spatial exponent coeff
constexpr float C2 = -LOG2E / 51200.0f;   // bilateral spatial coeff
constexpr float C3 = -LOG2E / 6.0f;       // bilateral intensity coeff

// LDS pool layout (bytes, 16-aligned)
constexpr int O_SSH  = 0;         // float[3136] s, linear image order
constexpr int O_GSRT = 12544;     // float[3136] g, sorted order
                                  // (init: H u16[49][256]=25088B overlays SSH+GSRT)
constexpr int O_MSRT = 25088;     // u16[3136]  sorted pos -> linear pixel idx
constexpr int O_OFF  = 31360;     // u32[257]   bucket offsets (pad 1040)
constexpr int O_WSX  = 32400;     // float[16][56] per-j row weights (aligned)
constexpr int O_WSY  = 35984;     // float[16][56] per-j column weights
constexpr int O_ROWC = 39568;     // float[56][17] row-conv out (pad stride 17)
constexpr int POOLSZ = 43376;

#define REDUCE32(v) \
    { v += __shfl_xor(v, 1); v += __shfl_xor(v, 2); v += __shfl_xor(v, 4); \
      v += __shfl_xor(v, 8); v += __shfl_xor(v, 16); }

__global__ __launch_bounds__(NTHR) void crf_all(
    const float* __restrict__ inp,
    const float* __restrict__ spw, const float* __restrict__ blw,
    const float* __restrict__ cmw,
    float* sbufs, float* __restrict__ out)
{
    __shared__ __align__(16) unsigned char pool[POOLSZ];
    float*  s_sh  = (float*)(pool + O_SSH);
    float4* s_sh4 = (float4*)(pool + O_SSH);
    float*  g_srt = (float*)(pool + O_GSRT);
    unsigned short* m_srt = (unsigned short*)(pool + O_MSRT);
    unsigned*       offs  = (unsigned*)(pool + O_OFF);
    float*  wsx   = (float*)(pool + O_WSX);
    float*  wsy   = (float*)(pool + O_WSY);
    float*  rowc  = (float*)(pool + O_ROWC);
    unsigned short* H  = (unsigned short*)(pool + O_SSH);   // init union (25088B)
    unsigned*       Hz = (unsigned*)(pool + O_SSH);

    const int t   = threadIdx.x;
    const int bid = blockIdx.x;
    const int sub = t & 31;
    const int jl  = t >> 5;               // 0..15
    const int j   = bid * JPB + jl;
    const int xj  = j % WIMG;             // blocks may straddle rows (16 ∤ 56)
    const int yj  = j / WIMG;
    const float xjf = (float)xj, yjf = (float)yj;

    const float uj = inp[j];
    const float gj = inp[NPIX + j] * 255.0f;

    // collapse the 2x2 weight matrices to 3 scalars
    const float e0 = cmw[2] - cmw[0];
    const float e1 = cmw[3] - cmw[1];
    const float alpha = e0 * (spw[0] + blw[0]) + e1 * (spw[2] + blw[2]);
    const float beta  = e0 * (spw[1] - spw[0]) + e1 * (spw[3] - spw[2]);
    const float gamma = e0 * (blw[1] - blw[0]) + e1 * (blw[3] - blw[2]);

    // ---- I0: zero H; build aligned per-j weight tables (outside H region)
    for (int i = t; i < 6272; i += NTHR) Hz[i] = 0u;
    for (int idx = t; idx < JPB * 56; idx += NTHR) {
        const int jlw = idx / 56, p = idx - jlw * 56;
        const int jj = bid * JPB + jlw;
        const float ddx = (float)(jj % WIMG - p);
        const float ddy = (float)(jj / WIMG - p);
        wsx[idx] = __builtin_amdgcn_exp2f(C1 * ddx * ddx);
        wsy[idx] = __builtin_amdgcn_exp2f(C1 * ddy * ddy);
    }
    __syncthreads();
    // ---- I1: per-chunk histogram (49 chunks x 64 px, single-owner rows)
    if (t < 49) {
        unsigned short* Hr = H + t * 256;
        const int mb = t * 64;
        for (int i = 0; i < 64; ++i) {
            int b = (int)(inp[NPIX + mb + i] * 255.0f);
            b = b > 255 ? 255 : b;
            Hr[b] = (unsigned short)(Hr[b] + 1);
        }
    }
    __syncthreads();
    // ---- I2: column prefix per bucket; totals -> offs[b]
    if (t < 256) {
        unsigned run = 0;
        for (int c = 0; c < 49; ++c) {
            unsigned short v = H[c * 256 + t];
            H[c * 256 + t] = (unsigned short)run;
            run += v;
        }
        offs[t] = run;
    }
    __syncthreads();
    // ---- I3: exclusive scan offs[0..255] (one wave, 4 buckets/lane)
    if (t < 64) {
        unsigned v0 = offs[4 * t], v1 = offs[4 * t + 1];
        unsigned v2 = offs[4 * t + 2], v3 = offs[4 * t + 3];
        unsigned sum = v0 + v1 + v2 + v3;
        unsigned sc = sum;
        for (int d = 1; d < 64; d <<= 1) {
            unsigned n = __shfl_up(sc, d);
            if (t >= d) sc += n;
        }
        unsigned base = sc - sum;
        offs[4 * t] = base;
        offs[4 * t + 1] = base + v0;
        offs[4 * t + 2] = base + v0 + v1;
        offs[4 * t + 3] = base + v0 + v1 + v2;
        if (t == 63) offs[256] = sc;               // = 3136
    }
    __syncthreads();
    // ---- I4: stable deterministic ranks -> m_srt
    if (t < 49) {
        unsigned short* Hr = H + t * 256;
        const int mb = t * 64;
        for (int i = 0; i < 64; ++i) {
            int b = (int)(inp[NPIX + mb + i] * 255.0f);
            b = b > 255 ? 255 : b;
            int r = (int)offs[b] + (int)Hr[b];
            Hr[b] = (unsigned short)(Hr[b] + 1);
            m_srt[r] = (unsigned short)(mb + i);
        }
    }
    __syncthreads();
    // ---- I5: H dead. Fill g_srt (sorted) and s_sh = u (linear).
    for (int p = t; p < NPIX; p += NTHR)
        g_srt[p] = inp[NPIX + (int)m_srt[p]] * 255.0f;
    {
        const float4* u4 = (const float4*)inp;
        for (int q = t; q < NQ; q += NTHR) s_sh4[q] = u4[q];
    }
    __syncthreads();

    // n_sp = Sx*Sy (exact separable)
    float sx, sy;
    {
        float dd = xjf - (float)sub;
        sx = __builtin_amdgcn_exp2f(C1 * dd * dd);
        if (sub + 32 < 56) {
            float d2 = xjf - (float)(sub + 32);
            sx += __builtin_amdgcn_exp2f(C1 * d2 * d2);
        }
        REDUCE32(sx);
        dd = yjf - (float)sub;
        sy = __builtin_amdgcn_exp2f(C1 * dd * dd);
        if (sub + 32 < 56) {
            float d2 = yjf - (float)(sub + 32);
            sy += __builtin_amdgcn_exp2f(C1 * d2 * d2);
        }
        REDUCE32(sy);
    }
    const float rnsp = 1.0f / (sx * sy);

    int bj = (int)gj; bj = bj > 255 ? 255 : bj;
    const int blo = (int)offs[bj < BAND ? 0 : bj - BAND];
    const int bhi = (int)offs[(bj + BAND > 255 ? 255 : bj + BAND) + 1];

    // separable spatial: row conv (56x16 = 896 outputs over 512 thr) + fold
    auto spatial = [&]() -> float {
        {
            const int y = t >> 4, c = t & 15;
            const float4* R = (const float4*)(wsx + c * 56);
            const float4* S = s_sh4 + y * 14;
            float acc = 0.f;
#pragma unroll
            for (int q = 0; q < 14; ++q) {
                float4 w = R[q], sv = S[q];
                acc = fmaf(w.x, sv.x, acc); acc = fmaf(w.y, sv.y, acc);
                acc = fmaf(w.z, sv.z, acc); acc = fmaf(w.w, sv.w, acc);
            }
            rowc[y * 17 + c] = acc;
        }
        {
            const int idx = t + NTHR;           // 512..895
            if (idx < 56 * 16) {
                const int y = idx >> 4, c = idx & 15;
                const float4* R = (const float4*)(wsx + c * 56);
                const float4* S = s_sh4 + y * 14;
                float acc = 0.f;
#pragma unroll
                for (int q = 0; q < 14; ++q) {
                    float4 w = R[q], sv = S[q];
                    acc = fmaf(w.x, sv.x, acc); acc = fmaf(w.y, sv.y, acc);
                    acc = fmaf(w.z, sv.z, acc); acc = fmaf(w.w, sv.w, acc);
                }
                rowc[y * 17 + c] = acc;
            }
        }
        __syncthreads();
        const float* wy = wsy + jl * 56;
        float part = wy[sub] * rowc[sub * 17 + jl];
        if (sub + 32 < 56)
            part = fmaf(wy[sub + 32], rowc[(sub + 32) * 17 + jl], part);
        REDUCE32(part);
        return part;
    };

    // bilateral band pass over sorted positions [blo,bhi), stride 32
    auto bilateral = [&](float* nacc_out) -> float {
        float acc = 0.f, nacc = 0.f;
        for (int p = blo + sub; p < bhi; p += 32) {
            const int m = (int)m_srt[p];
            const float gv = g_srt[p];
            const float sv = s_sh[m];
            const int yi = (m * 9363) >> 19;       // m/56 (exact for m<3136)
            const int xi = m - yi * 56;
            const float ux = (float)xi - xjf, vy = (float)yi - yjf;
            const float r2 = fmaf(ux, ux, vy * vy);
            const float dg = gv - gj;
            const float w = __builtin_amdgcn_exp2f(fmaf(dg * C3, dg, r2 * C2));
            acc = fmaf(w, sv, acc);
            if (nacc_out) nacc += w;
        }
        REDUCE32(acc);
        if (nacc_out) { REDUCE32(nacc); *nacc_out = nacc; }
        return acc;
    };

    // publish (leader lanes, straight out of the reduce -- no barrier) +
    // per-thread tight zero-sentinel spin + restage + ONE barrier.
    // Safety of no pre-poll barrier: detection requires all 3136 j's
    // published; a j publishes only after its 32-lane group's shfl-reduce,
    // which requires every group lane's s_sh/rowc reads to have executed.
    auto publish_sync = [&](float s, float* buf) {
        if (sub == 0)
            __hip_atomic_store(&buf[j], s, __ATOMIC_RELAXED,
                               __HIP_MEMORY_SCOPE_AGENT);
        const float4* src = (const float4*)buf;
        float4 a, b;
        const bool two = (t < Q2);
        bool da = false, db = !two;
        for (;;) {
            if (!da)
                asm volatile("global_load_dwordx4 %0, %1, off sc0 sc1"
                             : "=&v"(a) : "v"(src + t));
            if (!db)
                asm volatile("global_load_dwordx4 %0, %1, off sc0 sc1"
                             : "=&v"(b) : "v"(src + NTHR + t));
            asm volatile("s_waitcnt vmcnt(0)" ::: "memory");
            if (!da) da = (fminf(fminf(a.x, a.y), fminf(a.z, a.w)) != 0.0f);
            if (!db) db = (fminf(fminf(b.x, b.y), fminf(b.z, b.w)) != 0.0f);
            if (da && db) break;                    // exec mask narrows wave
        }
        s_sh4[t] = a;
        if (two) s_sh4[NTHR + t] = b;
        __syncthreads();                            // s_sh fully fresh
    };

    const float base = 2.0f * uj - 1.0f - alpha;
    float rnbl, s;

    // ---- iteration 0 (s = u), also accumulates n_bl over the band
    {
        float tsp = spatial();
        float nacc;
        float acc = bilateral(&nacc);
        rnbl = 1.0f / nacc;
        float d = base - beta * (tsp * rnsp) - gamma * (acc * rnbl);
        s = 1.0f / (1.0f + __builtin_amdgcn_exp2f(-d * LOG2E));
    }
    publish_sync(s, sbufs);

    // ---- iterations 1..9
    for (int k = 1; k < 10; ++k) {
        float tsp = spatial();
        float acc = bilateral(nullptr);
        float d = base - beta * (tsp * rnsp) - gamma * (acc * rnbl);
        s = 1.0f / (1.0f + __builtin_amdgcn_exp2f(-d * LOG2E));
        if (k < 9) publish_sync(s, sbufs + k * NPIX);
        else if (sub == 0) out[j] = s;   // softmax(q)[1] = sigmoid(d)
    }
}

}  // namespace

extern "C" void kernel_launch(void* const* d_in, const int* in_sizes, int n_in,
                              void* d_out, int out_size, void* d_ws, size_t ws_size,
                              hipStream_t stream) {
    const float* inp = (const float*)d_in[0];
    const float* spw = (const float*)d_in[1];
    const float* blw = (const float*)d_in[2];
    const float* cmw = (const float*)d_in[3];
    float* sbufs = (float*)d_ws;          // 9 x 3136 floats, zero = "not yet"
    float* out = (float*)d_out;

    hipMemsetAsync(sbufs, 0, NBUF * NPIX * sizeof(float), stream);
    crf_all<<<dim3(NBLK), dim3(NTHR), 0, stream>>>(inp, spw, blw, cmw,
                                                   sbufs, out);
}